// Round 8
// baseline (90.551 us; speedup 1.0000x reference)
//
#include <hip/hip_runtime.h>

// Hungarian matcher: B=32 batches, Q=300 preds (cols), T=50 truths (rows).
// 256 threads/block: 4 waves build the cost matrix + segmented row-min;
// wave 0 solves the LSA with all state in distributed registers.
// __launch_bounds__(256,1): no scratch spills. TRAJECTORY LOCKED TO R5:
// the instance (seed 0) contains cost ties, so the reference's answer is
// trajectory-dependent (R6's column-reduction duals FAILED). All changes
// since are bit-exact reorderings: two-stage u32 DPP min == same 64-bit
// min; v1g = readlane(v1, winner-lane) == the carried winning value;
// cost-row PREFETCH only moves immutable LDS reads earlier.
// Pipeline: row-min u + greedy claim (v=0) -> JV augmenting-row-reduction
// (<=6 requeues/row) -> Dijkstra fallback. Exact f64 duals.

#define NQ 300
#define NT 50
#define NSLOT 5    // ceil(300/64)
#define STRIDE 301
#define NTHREADS 256
#define ARR_CAP 6

typedef unsigned long long u64_t;

__device__ __forceinline__ u64_t minu64(u64_t a, u64_t b) { return a < b ? a : b; }
__device__ __forceinline__ unsigned minu32(unsigned a, unsigned b) { return a < b ? a : b; }

// monotone total-order mapping f64 <-> u64 (handles negatives)
__device__ __forceinline__ u64_t f64_key(double d) {
    u64_t u = __builtin_bit_cast(u64_t, d);
    u ^= (u64_t)((long long)u >> 63) | 0x8000000000000000ull;
    return u;
}
__device__ __forceinline__ double key_f64(u64_t k) {
    u64_t u = (k >> 63) ? (k ^ 0x8000000000000000ull) : ~k;
    return __builtin_bit_cast(double, u);
}
// low 9 bits = column index (unique winner; tie -> smaller column)
__device__ __forceinline__ u64_t pack_key(double d, int j) {
    return (f64_key(d) & ~511ull) | (u64_t)(unsigned)j;
}

template<int CTRL, int RMASK>
__device__ __forceinline__ unsigned dpp32(unsigned x) {
    return (unsigned)__builtin_amdgcn_update_dpp((int)x, (int)x, CTRL, RMASK, 0xf, false);
}

// full-wave u32 min, broadcast to all lanes (6 DPP steps + readlane)
__device__ __forceinline__ unsigned wave_min_u32(unsigned k) {
    k = minu32(k, dpp32<0x121, 0xf>(k));  // row_ror:1 (16-lane rows)
    k = minu32(k, dpp32<0x122, 0xf>(k));  // row_ror:2
    k = minu32(k, dpp32<0x124, 0xf>(k));  // row_ror:4
    k = minu32(k, dpp32<0x128, 0xf>(k));  // row_ror:8
    k = minu32(k, dpp32<0x142, 0xa>(k));  // row_bcast15 -> rows 1,3
    k = minu32(k, dpp32<0x143, 0xc>(k));  // row_bcast31 -> rows 2,3
    return (unsigned)__builtin_amdgcn_readlane((int)k, 63);
}

// exact 64-bit wave min via two 32-bit stages (lexicographic)
__device__ __forceinline__ u64_t wave_min_u64_2s(u64_t k) {
    unsigned hi = (unsigned)(k >> 32);
    unsigned mh = wave_min_u32(hi);
    unsigned lo = (hi == mh) ? (unsigned)k : 0xffffffffu;
    unsigned ml = wave_min_u32(lo);
    return ((u64_t)mh << 32) | ml;
}

__device__ __forceinline__ u64_t readlane_u64(u64_t u, int l) {
    int lo = __builtin_amdgcn_readlane((int)(unsigned)(u & 0xffffffffull), l);
    int hi = __builtin_amdgcn_readlane((int)(unsigned)(u >> 32), l);
    return ((u64_t)(unsigned)hi << 32) | (u64_t)(unsigned)lo;
}
__device__ __forceinline__ double readlane_f64(double x, int l) {
    return __builtin_bit_cast(double, readlane_u64(__builtin_bit_cast(u64_t, x), l));
}

__device__ __forceinline__ void wave_sync() { __builtin_amdgcn_wave_barrier(); }

// unrolled dynamic-index selects
#define SEL5(res, a, kidx) do { (res) = a[0]; \
    if ((kidx) == 1) (res) = a[1]; if ((kidx) == 2) (res) = a[2]; \
    if ((kidx) == 3) (res) = a[3]; if ((kidx) == 4) (res) = a[4]; } while (0)
#define SET5(a, kidx, val) do { \
    if ((kidx) == 0) a[0] = (val); if ((kidx) == 1) a[1] = (val); \
    if ((kidx) == 2) a[2] = (val); if ((kidx) == 3) a[3] = (val); \
    if ((kidx) == 4) a[4] = (val); } while (0)

__global__ __launch_bounds__(NTHREADS, 1) void hungarian_kernel(
    const float* __restrict__ pred, const float* __restrict__ truth,
    int* __restrict__ out)
{
#pragma clang fp contract(off)
    const int b = blockIdx.x;
    const int tid = threadIdx.x;
    const int lane = tid & 63;
    const int wav = tid >> 6;

    __shared__ float cost[NT * STRIDE];  // 60200 B
    __shared__ int claim[NQ];            // 1200 B
    __shared__ double sh_short[NQ];      // 2400 B (phase2 scratch: smin/samin)
    __shared__ int sh_c4r[NT];           // 200 B  (total 64000 B)

    const float4* pb4 = (const float4*)(pred + b * NQ * 4);
    const float4* tb4 = (const float4*)(truth + b * NT * 4);

    // ---- phase 1: cost matrix, all 4 waves (reference op order, no fma) ----
    for (int idx = tid; idx < NT * NQ; idx += NTHREADS) {
        int t = idx / NQ;
        int q = idx - t * NQ;
        float4 p = pb4[q];
        float4 tt = tb4[t];
        float pcx = p.x, pcy = p.y, pw = p.z, ph = p.w;
        float tcx = tt.x, tcy = tt.y, tw = tt.z, th = tt.w;
        float cb = ((fabsf(pcx-tcx) + fabsf(pcy-tcy)) + fabsf(pw-tw)) + fabsf(ph-th);
        float px1 = pcx - 0.5f*pw, py1 = pcy - 0.5f*ph;
        float px2 = pcx + 0.5f*pw, py2 = pcy + 0.5f*ph;
        float tx1 = tcx - 0.5f*tw, ty1 = tcy - 0.5f*th;
        float tx2 = tcx + 0.5f*tw, ty2 = tcy + 0.5f*th;
        float area1 = (px2-px1)*(py2-py1);
        float area2 = (tx2-tx1)*(ty2-ty1);
        float ltx = fmaxf(px1, tx1), lty = fmaxf(py1, ty1);
        float rbx = fminf(px2, tx2), rby = fminf(py2, ty2);
        float w = fmaxf(rbx-ltx, 0.f), h = fmaxf(rby-lty, 0.f);
        float inter = w*h;
        float uni = (area1 + area2) - inter;
        float iou = inter/uni;
        float ex1 = fminf(px1,tx1), ey1 = fminf(py1,ty1);
        float ex2 = fmaxf(px2,tx2), ey2 = fmaxf(py2,ty2);
        float ew = fmaxf(ex2-ex1, 0.f), eh = fmaxf(ey2-ey1, 0.f);
        float ae = ew*eh;
        float g = iou - (ae - uni)/ae;
        cost[t*STRIDE + q] = 5.0f*cb + 2.0f*(-g);
    }
    for (int j = tid; j < NQ; j += NTHREADS) claim[j] = 0x7fffffff;
    __syncthreads();

    // ---- phase 2a: segmented row-min partials (200 threads, 75 cols each) ----
    float* smin = (float*)sh_short;          // [4][50] f32 partial mins
    int* samin = (int*)(smin + 200);         // [4][50] argmins
    if (tid < 200) {
        int row = tid % 50, seg = tid / 50;
        int c0 = seg * 75;
        const float* rp = cost + row * STRIDE + c0;
        float m = __builtin_inff(); int a = 0;
        for (int c = 0; c < 75; ++c) {
            float x = rp[c];
            if (x < m) { m = x; a = c0 + c; }   // strict < -> first occurrence
        }
        smin[seg*50 + row] = m;
        samin[seg*50 + row] = a;
    }
    __syncthreads();

    // ---- phase 2b: combine + greedy claim (wave0 lanes 0..49) ----
    float rm = __builtin_inff();
    int ram = 0;
    if (tid < NT) {
        rm = smin[tid]; ram = samin[tid];
        for (int s = 1; s < 4; ++s) {
            float ms = smin[s*50 + tid]; int as = samin[s*50 + tid];
            if (ms < rm || (ms == rm && as < ram)) { rm = ms; ram = as; }
        }
        atomicMin(&claim[ram], tid);   // greedy claim: smallest row wins
    }
    __syncthreads();
    if (wav != 0) return;              // no barriers below this point

    // ---- wave-0 distributed solver state (v = 0: R5 trajectory) ----
    double u_reg = (tid < NT) ? (double)rm : 0.0;  // lane t: u[t]
    int c4r = -1;                                  // lane t: col4row[t]
    if (tid < NT && claim[ram] == tid) c4r = ram;
    double v_reg[NSLOT];
    int r4c_reg[NSLOT];
#pragma unroll
    for (int k = 0; k < NSLOT; ++k) {
        int j = lane + (k << 6);
        v_reg[k] = 0.0;
        int cl = (j < NQ) ? claim[j] : 0x7fffffff;
        r4c_reg[k] = (cl != 0x7fffffff) ? cl : -1;
    }
    int att_cnt = 0;                               // lane t: requeues of row t
    u64_t arr = __ballot(tid < NT && c4r < 0);
    u64_t dij = 0;

    // ---- phase 3: JV augmenting row reduction (<= ARR_CAP requeues/row) ----
    // Steady-state loop with next-row cost prefetch: the displaced row (and
    // hence the next queue head) is known right after the argmin reduce, so
    // the next row's LDS reads overlap the second-min reduction.
    int i_cur = -1;
    float cr[NSLOT];
    if (arr) {
        i_cur = __builtin_ctzll(arr);
        arr &= arr - 1;
#pragma unroll
        for (int k = 0; k < NSLOT; ++k) {
            int j = lane + (k << 6);
            cr[k] = (j < NQ) ? cost[i_cur * STRIDE + j] : 0.f;
        }
    }
    while (i_cur >= 0) {
        const int i = i_cur;
        u64_t k1 = ~0ull;
        double v1 = __builtin_inf(), v2 = __builtin_inf();
#pragma unroll
        for (int k = 0; k < NSLOT; ++k) {
            int j = lane + (k << 6);
            if (j < NQ) {
                double m = (double)cr[k] - v_reg[k];
                u64_t kk = pack_key(m, j);
                if (kk < k1) { v2 = v1; v1 = m; k1 = kk; }
                else v2 = fmin(v2, m);
            }
        }
        u64_t kmin = wave_min_u64_2s(k1);          // exact argmin (R5 winner)
        int j1 = (int)(kmin & 511ull);
        int kj = j1 >> 6, lj = j1 & 63;
        double v1g = readlane_f64(v1, lj);         // winner's carried exact m
        int rsel; SEL5(rsel, r4c_reg, kj);
        int r = __builtin_amdgcn_readlane(rsel, lj);
        // early queue update (same values/order as R5's end-of-loop update)
        if (r >= 0) {
            int ac = __builtin_amdgcn_readlane(att_cnt, r) + 1;
            if (lane == r) att_cnt = ac;
            u64_t rb = 1ull << r;
            if (ac <= ARR_CAP) arr |= rb; else dij |= rb;
        }
        int i_next = -1;
        if (arr) { i_next = __builtin_ctzll(arr); arr &= arr - 1; }
        // prefetch next row + cij broadcast (overlap the v2g reduction)
        float ncr[NSLOT];
        int prow = (i_next >= 0) ? i_next : 0;
#pragma unroll
        for (int k = 0; k < NSLOT; ++k) {
            int j = lane + (k << 6);
            ncr[k] = (j < NQ) ? cost[prow * STRIDE + j] : 0.f;
        }
        float cijf = cost[i * STRIDE + j1];        // uniform broadcast read
        // exact second-min: set-min over {winner.v2} U {others.v1}
        double cand = (lane == lj) ? v2 : v1;
        double v2g = key_f64(wave_min_u64_2s(f64_key(cand)));
        if (r < 0) {
            if (lane == lj) SET5(r4c_reg, kj, i);
            if (lane == i) { c4r = j1; u_reg = v1g; }
        } else {
            double cij = (double)cijf;
            if (lane == lj) { SET5(r4c_reg, kj, i); SET5(v_reg, kj, cij - v2g); }
            if (lane == i) { c4r = j1; u_reg = v2g; }
            if (lane == r) c4r = -1;
        }
        i_cur = i_next;
#pragma unroll
        for (int k = 0; k < NSLOT; ++k) cr[k] = ncr[k];
    }

    // ---- phase 4: Dijkstra (successive shortest paths) for leftovers ----
    while (dij) {
        int cur = __builtin_ctzll(dij);
        dij &= dij - 1;
        unsigned oncol = 0;
        u64_t onrow = 0;
        double short_reg[NSLOT];
        u64_t short_key[NSLOT];                  // +inf once column on tree
        int path_reg[NSLOT];
#pragma unroll
        for (int k = 0; k < NSLOT; ++k) {
            short_reg[k] = __builtin_inf(); short_key[k] = ~0ull; path_reg[k] = -1;
        }
        double min_val = 0.0;
        int i = cur, sink = -1;
        float dr[NSLOT];
#pragma unroll
        for (int k = 0; k < NSLOT; ++k) {
            int j = lane + (k << 6);
            dr[k] = (j < NQ) ? cost[cur * STRIDE + j] : 0.f;
        }

        while (sink < 0) {
            onrow |= 1ull << i;
            double u_i = readlane_f64(u_reg, i);
            u64_t bk = ~0ull;
#pragma unroll
            for (int k = 0; k < NSLOT; ++k) {
                int j = lane + (k << 6);
                if (j < NQ && !((oncol >> k) & 1u)) {
                    double d = ((min_val + (double)dr[k]) - u_i) - v_reg[k];
                    if (d < short_reg[k]) {
                        short_reg[k] = d; path_reg[k] = i;
                        short_key[k] = pack_key(d, j);
                    }
                }
                bk = minu64(bk, short_key[k]);
            }
            bk = wave_min_u64_2s(bk);              // exact same winner as R5
            int j = (int)(bk & 511ull);
            int kj = j >> 6, lj = j & 63;
            int rsel; SEL5(rsel, r4c_reg, kj);
            int r = __builtin_amdgcn_readlane(rsel, lj);
            // prefetch next tree row while min_val/state updates run
            float ndr[NSLOT];
            int prow = (r >= 0) ? r : 0;
#pragma unroll
            for (int k = 0; k < NSLOT; ++k) {
                int jq = lane + (k << 6);
                ndr[k] = (jq < NQ) ? cost[prow * STRIDE + jq] : 0.f;
            }
            double ssel; SEL5(ssel, short_reg, kj);
            min_val = readlane_f64(ssel, lj);      // exact winning value
            if (lane == lj) { oncol |= 1u << kj; SET5(short_key, kj, ~0ull); }
            if (r < 0) {
                sink = j;
            } else {
                i = r;
#pragma unroll
                for (int k = 0; k < NSLOT; ++k) dr[k] = ndr[k];
            }
        }

        // dump shortest for the u-update gather (per-lane variable index)
#pragma unroll
        for (int k = 0; k < NSLOT; ++k) {
            int j = lane + (k << 6);
            if (j < NQ) sh_short[j] = short_reg[k];
        }
        wave_sync();
        double ss = (tid < NT && c4r >= 0) ? sh_short[c4r] : 0.0;
        if (tid < NT) {
            if (tid == cur) u_reg = u_reg + min_val;
            else if ((onrow >> tid) & 1ull) u_reg = u_reg + (min_val - ss);
        }
#pragma unroll
        for (int k = 0; k < NSLOT; ++k) {
            int j = lane + (k << 6);
            if (j < NQ && ((oncol >> k) & 1u))
                v_reg[k] = v_reg[k] - (min_val - short_reg[k]);
        }

        // augmentation walk: registers + readlane only
        int jj = sink;
        while (true) {
            int kk2 = jj >> 6, ll = jj & 63;
            int psel; SEL5(psel, path_reg, kk2);
            int ii = __builtin_amdgcn_readlane(psel, ll);
            if (lane == ll) SET5(r4c_reg, kk2, ii);
            int nj = __builtin_amdgcn_readlane(c4r, ii);  // old col4row[ii]
            if (lane == ii) c4r = jj;
            jj = nj;
            if (ii == cur) break;
        }
    }

    // ---- output: pairs (pred=col4row[t], truth=t) sorted by pred index ----
    if (tid < NT) sh_c4r[tid] = c4r;
    wave_sync();
    if (tid < NT) {
        int it = c4r;
        int rank = 0;
        for (int t2 = 0; t2 < NT; ++t2) rank += (sh_c4r[t2] < it) ? 1 : 0;
        out[b * 2 * NT + rank] = it;             // row 0: sorted pred indices
        out[b * 2 * NT + NT + rank] = tid;       // row 1: matching truth indices
    }
}

extern "C" void kernel_launch(void* const* d_in, const int* in_sizes, int n_in,
                              void* d_out, int out_size, void* d_ws, size_t ws_size,
                              hipStream_t stream) {
    const float* pred  = (const float*)d_in[0];   // (32, 300, 4) f32
    const float* truth = (const float*)d_in[1];   // (32, 50, 4)  f32
    int* out = (int*)d_out;                       // (32, 2, 50)  int32
    hungarian_kernel<<<32, NTHREADS, 0, stream>>>(pred, truth, out);
}

// Round 9
// 87.012 us; speedup vs baseline: 1.0407x; 1.0407x over previous
//
#include <hip/hip_runtime.h>

// Hungarian matcher: B=32 batches, Q=300 preds (cols), T=50 truths (rows).
// 256 threads/block: 4 waves build the cost matrix + segmented row-min;
// wave 0 solves the LSA with all state in distributed registers.
// TRAJECTORY LOCKED TO R5: instance has cost ties (R6's better duals changed
// the final assignment), so every change must reproduce the R5 update
// sequence bit-for-bit. R9 = R7 structure + three exact-equivalent cuts:
//   (1) v1g = readlane(winner v1)  == R7's cij - readlane(v_old) bitwise
//   (2) cij/v2g computed only on the displace path (unused on assign)
//   (3) stage-2 of the 64-bit DPP min skipped when the hi-32 min is unique
// Pipeline: row-min u + greedy claim (v=0) -> JV augmenting-row-reduction
// (<=6 requeues/row) -> Dijkstra fallback. Exact f64 duals.

#define NQ 300
#define NT 50
#define NSLOT 5    // ceil(300/64)
#define STRIDE 301
#define NTHREADS 256
#define ARR_CAP 6

typedef unsigned long long u64_t;

__device__ __forceinline__ u64_t minu64(u64_t a, u64_t b) { return a < b ? a : b; }
__device__ __forceinline__ unsigned minu32(unsigned a, unsigned b) { return a < b ? a : b; }

// monotone total-order mapping f64 <-> u64 (handles negatives)
__device__ __forceinline__ u64_t f64_key(double d) {
    u64_t u = __builtin_bit_cast(u64_t, d);
    u ^= (u64_t)((long long)u >> 63) | 0x8000000000000000ull;
    return u;
}
__device__ __forceinline__ double key_f64(u64_t k) {
    u64_t u = (k >> 63) ? (k ^ 0x8000000000000000ull) : ~k;
    return __builtin_bit_cast(double, u);
}
// low 9 bits = column index (unique winner; tie -> smaller column)
__device__ __forceinline__ u64_t pack_key(double d, int j) {
    return (f64_key(d) & ~511ull) | (u64_t)(unsigned)j;
}

template<int CTRL, int RMASK>
__device__ __forceinline__ unsigned dpp32(unsigned x) {
    return (unsigned)__builtin_amdgcn_update_dpp((int)x, (int)x, CTRL, RMASK, 0xf, false);
}

// full-wave u32 min, broadcast to all lanes (6 DPP steps + readlane)
__device__ __forceinline__ unsigned wave_min_u32(unsigned k) {
    k = minu32(k, dpp32<0x121, 0xf>(k));  // row_ror:1 (16-lane rows)
    k = minu32(k, dpp32<0x122, 0xf>(k));  // row_ror:2
    k = minu32(k, dpp32<0x124, 0xf>(k));  // row_ror:4
    k = minu32(k, dpp32<0x128, 0xf>(k));  // row_ror:8
    k = minu32(k, dpp32<0x142, 0xa>(k));  // row_bcast15 -> rows 1,3
    k = minu32(k, dpp32<0x143, 0xc>(k));  // row_bcast31 -> rows 2,3
    return (unsigned)__builtin_amdgcn_readlane((int)k, 63);
}

// exact 64-bit wave min via two 32-bit stages; stage 2 collapses to one
// readlane when the hi-32 min is held by a single lane (common case).
__device__ __forceinline__ u64_t wave_min_u64_2s(u64_t k) {
    unsigned hi = (unsigned)(k >> 32);
    unsigned mh = wave_min_u32(hi);
    u64_t bal = __ballot(hi == mh);
    unsigned ml;
    if (bal & (bal - 1)) {                 // multiple hi-min lanes: reduce lo
        unsigned lo = (hi == mh) ? (unsigned)k : 0xffffffffu;
        ml = wave_min_u32(lo);
    } else {                               // unique: fetch lo directly
        int l = (int)__builtin_ctzll(bal);
        ml = (unsigned)__builtin_amdgcn_readlane((int)(unsigned)k, l);
    }
    return ((u64_t)mh << 32) | ml;
}

__device__ __forceinline__ u64_t readlane_u64(u64_t u, int l) {
    int lo = __builtin_amdgcn_readlane((int)(unsigned)(u & 0xffffffffull), l);
    int hi = __builtin_amdgcn_readlane((int)(unsigned)(u >> 32), l);
    return ((u64_t)(unsigned)hi << 32) | (u64_t)(unsigned)lo;
}
__device__ __forceinline__ double readlane_f64(double x, int l) {
    return __builtin_bit_cast(double, readlane_u64(__builtin_bit_cast(u64_t, x), l));
}

__device__ __forceinline__ void wave_sync() { __builtin_amdgcn_wave_barrier(); }

// unrolled dynamic-index selects
#define SEL5(res, a, kidx) do { (res) = a[0]; \
    if ((kidx) == 1) (res) = a[1]; if ((kidx) == 2) (res) = a[2]; \
    if ((kidx) == 3) (res) = a[3]; if ((kidx) == 4) (res) = a[4]; } while (0)
#define SET5(a, kidx, val) do { \
    if ((kidx) == 0) a[0] = (val); if ((kidx) == 1) a[1] = (val); \
    if ((kidx) == 2) a[2] = (val); if ((kidx) == 3) a[3] = (val); \
    if ((kidx) == 4) a[4] = (val); } while (0)

__global__ __launch_bounds__(NTHREADS, 1) void hungarian_kernel(
    const float* __restrict__ pred, const float* __restrict__ truth,
    int* __restrict__ out)
{
#pragma clang fp contract(off)
    const int b = blockIdx.x;
    const int tid = threadIdx.x;
    const int lane = tid & 63;
    const int wav = tid >> 6;

    __shared__ float cost[NT * STRIDE];  // 60200 B
    __shared__ int claim[NQ];            // 1200 B
    __shared__ double sh_short[NQ];      // 2400 B (phase2 scratch: smin/samin)
    __shared__ int sh_c4r[NT];           // 200 B  (total 64000 B)

    const float4* pb4 = (const float4*)(pred + b * NQ * 4);
    const float4* tb4 = (const float4*)(truth + b * NT * 4);

    // ---- phase 1: cost matrix, all 4 waves (reference op order, no fma) ----
    for (int idx = tid; idx < NT * NQ; idx += NTHREADS) {
        int t = idx / NQ;
        int q = idx - t * NQ;
        float4 p = pb4[q];
        float4 tt = tb4[t];
        float pcx = p.x, pcy = p.y, pw = p.z, ph = p.w;
        float tcx = tt.x, tcy = tt.y, tw = tt.z, th = tt.w;
        float cb = ((fabsf(pcx-tcx) + fabsf(pcy-tcy)) + fabsf(pw-tw)) + fabsf(ph-th);
        float px1 = pcx - 0.5f*pw, py1 = pcy - 0.5f*ph;
        float px2 = pcx + 0.5f*pw, py2 = pcy + 0.5f*ph;
        float tx1 = tcx - 0.5f*tw, ty1 = tcy - 0.5f*th;
        float tx2 = tcx + 0.5f*tw, ty2 = tcy + 0.5f*th;
        float area1 = (px2-px1)*(py2-py1);
        float area2 = (tx2-tx1)*(ty2-ty1);
        float ltx = fmaxf(px1, tx1), lty = fmaxf(py1, ty1);
        float rbx = fminf(px2, tx2), rby = fminf(py2, ty2);
        float w = fmaxf(rbx-ltx, 0.f), h = fmaxf(rby-lty, 0.f);
        float inter = w*h;
        float uni = (area1 + area2) - inter;
        float iou = inter/uni;
        float ex1 = fminf(px1,tx1), ey1 = fminf(py1,ty1);
        float ex2 = fmaxf(px2,tx2), ey2 = fmaxf(py2,ty2);
        float ew = fmaxf(ex2-ex1, 0.f), eh = fmaxf(ey2-ey1, 0.f);
        float ae = ew*eh;
        float g = iou - (ae - uni)/ae;
        cost[t*STRIDE + q] = 5.0f*cb + 2.0f*(-g);
    }
    for (int j = tid; j < NQ; j += NTHREADS) claim[j] = 0x7fffffff;
    __syncthreads();

    // ---- phase 2a: segmented row-min partials (250 threads, 60 cols each) ----
    float* smin = (float*)sh_short;          // [5][50] f32 partial mins
    int* samin = (int*)(smin + 250);         // [5][50] argmins
    if (tid < 250) {
        int row = tid % 50, seg = tid / 50;
        int c0 = seg * 60;
        const float* rp = cost + row * STRIDE + c0;
        float m = __builtin_inff(); int a = 0;
        for (int c = 0; c < 60; ++c) {
            float x = rp[c];
            if (x < m) { m = x; a = c0 + c; }   // strict < -> first occurrence
        }
        smin[seg*50 + row] = m;
        samin[seg*50 + row] = a;
    }
    __syncthreads();

    // ---- phase 2b: combine + greedy claim (wave0 lanes 0..49) ----
    // (partition-independent: tie-break on full column index -> same (rm,ram))
    float rm = __builtin_inff();
    int ram = 0;
    if (tid < NT) {
        rm = smin[tid]; ram = samin[tid];
        for (int s = 1; s < 5; ++s) {
            float ms = smin[s*50 + tid]; int as = samin[s*50 + tid];
            if (ms < rm || (ms == rm && as < ram)) { rm = ms; ram = as; }
        }
        atomicMin(&claim[ram], tid);   // greedy claim: smallest row wins
    }
    __syncthreads();
    if (wav != 0) return;              // no barriers below this point

    // ---- wave-0 distributed solver state (v = 0: R5 trajectory) ----
    double u_reg = (tid < NT) ? (double)rm : 0.0;  // lane t: u[t]
    int c4r = -1;                                  // lane t: col4row[t]
    if (tid < NT && claim[ram] == tid) c4r = ram;
    double v_reg[NSLOT];
    int r4c_reg[NSLOT];
#pragma unroll
    for (int k = 0; k < NSLOT; ++k) {
        int j = lane + (k << 6);
        v_reg[k] = 0.0;
        int cl = (j < NQ) ? claim[j] : 0x7fffffff;
        r4c_reg[k] = (cl != 0x7fffffff) ? cl : -1;
    }
    int att_cnt = 0;                               // lane t: requeues of row t
    u64_t arr = __ballot(tid < NT && c4r < 0);
    u64_t dij = 0;

    // ---- phase 3: JV augmenting row reduction (<= ARR_CAP requeues/row) ----
    while (arr) {
        int i = __builtin_ctzll(arr);
        arr &= arr - 1;
        const float* crow = cost + i * STRIDE;
        u64_t k1 = ~0ull;
        double v1 = __builtin_inf(), v2 = __builtin_inf();
#pragma unroll
        for (int k = 0; k < NSLOT; ++k) {
            int j = lane + (k << 6);
            if (j < NQ) {
                double m = (double)crow[j] - v_reg[k];
                u64_t kk = pack_key(m, j);
                if (kk < k1) { v2 = v1; v1 = m; k1 = kk; }
                else v2 = fmin(v2, m);
            }
        }
        u64_t kmin = wave_min_u64_2s(k1);          // exact argmin (R5 winner)
        int j1 = (int)(kmin & 511ull);
        int kj = j1 >> 6, lj = j1 & 63;
        double v1g = readlane_f64(v1, lj);         // winner's carried exact m
        int rsel; SEL5(rsel, r4c_reg, kj);
        int r = __builtin_amdgcn_readlane(rsel, lj);
        if (r < 0) {
            // assign path: no cij, no second-min reduction needed
            if (lane == lj) SET5(r4c_reg, kj, i);
            if (lane == i) { c4r = j1; u_reg = v1g; }
        } else {
            double cij = (double)crow[j1];         // uniform broadcast read
            // exact second-min: set-min over {winner.v2} U {others.v1}
            double cand = (lane == lj) ? v2 : v1;
            double v2g = key_f64(wave_min_u64_2s(f64_key(cand)));
            if (lane == lj) { SET5(r4c_reg, kj, i); SET5(v_reg, kj, cij - v2g); }
            if (lane == i) { c4r = j1; u_reg = v2g; }
            if (lane == r) { c4r = -1; att_cnt++; }
            int ac = __builtin_amdgcn_readlane(att_cnt, r);
            u64_t rb = 1ull << r;
            if (ac <= ARR_CAP) arr |= rb; else dij |= rb;
        }
    }

    // ---- phase 4: Dijkstra (successive shortest paths) for leftovers ----
    while (dij) {
        int cur = __builtin_ctzll(dij);
        dij &= dij - 1;
        unsigned oncol = 0;
        u64_t onrow = 0;
        double short_reg[NSLOT];
        u64_t short_key[NSLOT];                  // +inf once column on tree
        int path_reg[NSLOT];
#pragma unroll
        for (int k = 0; k < NSLOT; ++k) {
            short_reg[k] = __builtin_inf(); short_key[k] = ~0ull; path_reg[k] = -1;
        }
        double min_val = 0.0;
        int i = cur, sink = -1;

        while (sink < 0) {
            onrow |= 1ull << i;
            double u_i = readlane_f64(u_reg, i);
            const float* crow = cost + i * STRIDE;
            u64_t bk = ~0ull;
#pragma unroll
            for (int k = 0; k < NSLOT; ++k) {
                int j = lane + (k << 6);
                if (j < NQ && !((oncol >> k) & 1u)) {
                    double d = ((min_val + (double)crow[j]) - u_i) - v_reg[k];
                    if (d < short_reg[k]) {
                        short_reg[k] = d; path_reg[k] = i;
                        short_key[k] = pack_key(d, j);
                    }
                }
                bk = minu64(bk, short_key[k]);
            }
            bk = wave_min_u64_2s(bk);              // exact same winner as R5
            int j = (int)(bk & 511ull);
            int kj = j >> 6, lj = j & 63;
            double ssel; SEL5(ssel, short_reg, kj);
            min_val = readlane_f64(ssel, lj);      // exact winning value
            if (lane == lj) { oncol |= 1u << kj; SET5(short_key, kj, ~0ull); }
            int rsel; SEL5(rsel, r4c_reg, kj);
            int r = __builtin_amdgcn_readlane(rsel, lj);
            if (r < 0) sink = j; else i = r;
        }

        // dump shortest for the u-update gather (per-lane variable index)
#pragma unroll
        for (int k = 0; k < NSLOT; ++k) {
            int j = lane + (k << 6);
            if (j < NQ) sh_short[j] = short_reg[k];
        }
        wave_sync();
        double ss = (tid < NT && c4r >= 0) ? sh_short[c4r] : 0.0;
        if (tid < NT) {
            if (tid == cur) u_reg = u_reg + min_val;
            else if ((onrow >> tid) & 1ull) u_reg = u_reg + (min_val - ss);
        }
#pragma unroll
        for (int k = 0; k < NSLOT; ++k) {
            int j = lane + (k << 6);
            if (j < NQ && ((oncol >> k) & 1u))
                v_reg[k] = v_reg[k] - (min_val - short_reg[k]);
        }

        // augmentation walk: registers + readlane only
        int jj = sink;
        while (true) {
            int kk2 = jj >> 6, ll = jj & 63;
            int psel; SEL5(psel, path_reg, kk2);
            int ii = __builtin_amdgcn_readlane(psel, ll);
            if (lane == ll) SET5(r4c_reg, kk2, ii);
            int nj = __builtin_amdgcn_readlane(c4r, ii);  // old col4row[ii]
            if (lane == ii) c4r = jj;
            jj = nj;
            if (ii == cur) break;
        }
    }

    // ---- output: pairs (pred=col4row[t], truth=t) sorted by pred index ----
    if (tid < NT) sh_c4r[tid] = c4r;
    wave_sync();
    if (tid < NT) {
        int it = c4r;
        int rank = 0;
        for (int t2 = 0; t2 < NT; ++t2) rank += (sh_c4r[t2] < it) ? 1 : 0;
        out[b * 2 * NT + rank] = it;             // row 0: sorted pred indices
        out[b * 2 * NT + NT + rank] = tid;       // row 1: matching truth indices
    }
}

extern "C" void kernel_launch(void* const* d_in, const int* in_sizes, int n_in,
                              void* d_out, int out_size, void* d_ws, size_t ws_size,
                              hipStream_t stream) {
    const float* pred  = (const float*)d_in[0];   // (32, 300, 4) f32
    const float* truth = (const float*)d_in[1];   // (32, 50, 4)  f32
    int* out = (int*)d_out;                       // (32, 2, 50)  int32
    hungarian_kernel<<<32, NTHREADS, 0, stream>>>(pred, truth, out);
}